// Round 1
// baseline (716.179 us; speedup 1.0000x reference)
//
#include <hip/hip_runtime.h>

// ---------------------------------------------------------------------------
// ExtraPositionPromptSABottleneck on MI355X (gfx950)
// B=8, DIMS=512, C=256, H=W=64, N=4096.
//
// Round 5:
//  - Algebraic factorization of the positional term: pos[c,n] = rel_h[c,h]
//    + rel_w[c,w]  =>  cp[n,m] = RH[h_n,m] + RW[w_n,m] with RH = rel_h^T e,
//    RW = rel_w^T e (tiny 128x4096x256 GEMM per batch).  gemm3b's K drops
//    512 -> 256 (attention scores = q.k^T only); RH/RW slices (66x128) are
//    staged in LDS (bf16, pad 132) and added in the epilogue.
//  - qp/ke merged into one qk[32768][512] buffer (q cols 0-255, k 256-511);
//    pos_prep_kernel removed.
//  - XCD-aware bijective block swizzle in gemm3b (4096 blocks % 8 == 0) so
//    each XCD chunk touches ~3MB of qk (fits per-XCD 4MB L2).
// ---------------------------------------------------------------------------

typedef __bf16 bf16;
typedef __attribute__((ext_vector_type(8))) __bf16 bf16x8;
typedef __attribute__((ext_vector_type(4))) float f32x4;

__device__ __forceinline__ float silu_f(float x) { return x / (1.f + __expf(-x)); }

__device__ __forceinline__ void zero_acc(f32x4 (&acc)[4][4])
{
#pragma unroll
    for (int i = 0; i < 4; ++i)
#pragma unroll
        for (int j = 0; j < 4; ++j)
            acc[i][j] = (f32x4){0.f, 0.f, 0.f, 0.f};
}

// ---- LDS-staged GEMM core: block 256 thr, tile 128x128, BK=32
__device__ __forceinline__ void load_lds16(const bf16* g, bf16* l)
{
    __builtin_amdgcn_global_load_lds(
        (const __attribute__((address_space(1))) unsigned int*)g,
        (__attribute__((address_space(3))) unsigned int*)l, 16, 0, 0);
}

// A: block's 128 rows, k-contig stride lda. B: block's 128 "cols", stride ldb.
// LDS slot (row, kb) holds global (row, kb ^ ((row>>1)&3)) -- XOR swizzle.
__device__ __forceinline__ void gemm_core_lds(
    const bf16* __restrict__ A, int lda,
    const bf16* __restrict__ B, int ldb,
    int K, f32x4 (&acc)[4][4])
{
    __shared__ bf16 As[128 * 32];
    __shared__ bf16 Bs[128 * 32];
    const int tid = threadIdx.x;
    const int wave = tid >> 6;
    const int lane = tid & 63;
    const int lm = lane & 15;
    const int kq = lane >> 4;
    const int m0 = (wave >> 1) * 64;
    const int n0 = (wave & 1) * 64;
    // staging: each thread supplies 16B per round; 2 rounds per matrix.
    const int srow = tid >> 2;                              // rows 0..63, +64
    const int skoff = (((tid & 3) ^ ((tid >> 3) & 3))) * 8; // swizzled k-block
    const int krd = (kq ^ ((lm >> 1) & 3)) * 8;             // read-side offset
    bf16* lA = As + tid * 8;            // LDS dest = wave_base + lane*16B
    bf16* lB = Bs + tid * 8;
    zero_acc(acc);
    for (int k0 = 0; k0 < K; k0 += 32) {
        const bf16* ga = A + (size_t)srow * lda + k0 + skoff;
        const bf16* gb = B + (size_t)srow * ldb + k0 + skoff;
        load_lds16(ga, lA);
        load_lds16(ga + (size_t)64 * lda, lA + 64 * 32);
        load_lds16(gb, lB);
        load_lds16(gb + (size_t)64 * ldb, lB + 64 * 32);
        __syncthreads();
        bf16x8 av[4], bv[4];
#pragma unroll
        for (int t = 0; t < 4; ++t)
            av[t] = *(const bf16x8*)(As + (m0 + t * 16 + lm) * 32 + krd);
#pragma unroll
        for (int t = 0; t < 4; ++t)
            bv[t] = *(const bf16x8*)(Bs + (n0 + t * 16 + lm) * 32 + krd);
#pragma unroll
        for (int i = 0; i < 4; ++i)
#pragma unroll
            for (int j = 0; j < 4; ++j)
                acc[i][j] = __builtin_amdgcn_mfma_f32_16x16x32_bf16(
                    av[i], bv[j], acc[i][j], 0, 0, 0);
        __syncthreads();
    }
}

// ------------------------------ prep kernels -------------------------------

__global__ __launch_bounds__(256) void prep_misc_kernel(
    const float* __restrict__ cv1_w,
    const float* __restrict__ qw, const float* __restrict__ qb,
    const float* __restrict__ kw, const float* __restrict__ kb,
    const float* __restrict__ vw, const float* __restrict__ vb,
    const float* __restrict__ ew, const float* __restrict__ eb,
    const float* __restrict__ cv2_w,
    const float* __restrict__ g1, const float* __restrict__ b1,
    const float* __restrict__ m1, const float* __restrict__ v1,
    const float* __restrict__ g2, const float* __restrict__ b2,
    const float* __restrict__ m2, const float* __restrict__ v2,
    const float* __restrict__ rel_h, const float* __restrict__ rel_w,
    bf16* __restrict__ w1b, bf16* __restrict__ wqkve, bf16* __restrict__ w2b,
    bf16* __restrict__ posT,
    float* __restrict__ biasq,
    float* __restrict__ bn1s, float* __restrict__ bn1h,
    float* __restrict__ bn2s, float* __restrict__ bn2h)
{
    int idx = blockIdx.x * 256 + threadIdx.x;
    if (idx < 131072) { w1b[idx] = (bf16)cv1_w[idx]; return; }
    idx -= 131072;
    if (idx < 262144) {
        int j = idx >> 8, c = idx & 255;
        int p = j >> 8, r = j & 255;
        const float* w = (p == 0) ? qw : (p == 1) ? kw : (p == 2) ? vw : ew;
        wqkve[idx] = (bf16)w[r * 256 + c];
        return;
    }
    idx -= 262144;
    if (idx < 131072) { w2b[idx] = (bf16)cv2_w[idx]; return; }
    idx -= 131072;
    if (idx < 1024) {
        int p = idx >> 8, r = idx & 255;
        const float* bb = (p == 0) ? qb : (p == 1) ? kb : (p == 2) ? vb : eb;
        biasq[idx] = bb[r];
        return;
    }
    idx -= 1024;
    if (idx < 256) {
        float s = g1[idx] * rsqrtf(v1[idx] + 1e-5f);
        bn1s[idx] = s;
        bn1h[idx] = b1[idx] - m1[idx] * s;
        return;
    }
    idx -= 256;
    if (idx < 512) {
        float s = g2[idx] * rsqrtf(v2[idx] + 1e-5f);
        bn2s[idx] = s;
        bn2h[idx] = b2[idx] - m2[idx] * s;
        return;
    }
    idx -= 512;
    if (idx < 32768) {
        // posT[r][c], r<64: rel_h[c][r]; r>=64: rel_w[c][r-64]
        int r = idx >> 8, c = idx & 255;
        posT[idx] = (bf16)((r < 64) ? rel_h[c * 64 + r] : rel_w[c * 64 + (r - 64)]);
        return;
    }
}

__global__ __launch_bounds__(256) void zero_lsum_kernel(float* __restrict__ p)
{
    p[blockIdx.x * 256 + threadIdx.x] = 0.f;
}

// xt[b*4096+n][d] = (bf16) x[b][d][n]
__global__ __launch_bounds__(256) void transpose_x_kernel(
    const float* __restrict__ x, bf16* __restrict__ xt)
{
    __shared__ float tile[64][65];
    int b = blockIdx.z;
    int n0 = blockIdx.x * 64;
    int d0 = blockIdx.y * 64;
    int tx = threadIdx.x & 63, ty = threadIdx.x >> 6;
#pragma unroll
    for (int i = 0; i < 16; ++i) {
        int d = i * 4 + ty;
        tile[d][tx] = x[((size_t)(b * 512 + d0 + d)) * 4096 + n0 + tx];
    }
    __syncthreads();
#pragma unroll
    for (int i = 0; i < 16; ++i) {
        int n = i * 4 + ty;
        xt[((size_t)(b * 4096 + n0 + n)) * 512 + d0 + tx] = (bf16)tile[tx][n];
    }
}

// v_cm[b][c][m] = v_nm[b*4096+m][c]
__global__ __launch_bounds__(256) void transpose_v_kernel(
    const bf16* __restrict__ v_nm, bf16* __restrict__ v_cm)
{
    __shared__ float tile[64][65];
    int b = blockIdx.z;
    int m0 = blockIdx.x * 64;
    int c0 = blockIdx.y * 64;
    int tx = threadIdx.x & 63, ty = threadIdx.x >> 6;
#pragma unroll
    for (int i = 0; i < 16; ++i) {
        int m = i * 4 + ty;
        tile[m][tx] = (float)v_nm[((size_t)(b * 4096 + m0 + m)) * 256 + c0 + tx];
    }
    __syncthreads();
#pragma unroll
    for (int i = 0; i < 16; ++i) {
        int c = i * 4 + ty;
        v_cm[((size_t)(b * 256 + c0 + c)) * 4096 + m0 + tx] = (bf16)tile[tx][c];
    }
}

// ------------------------------ GEMM kernels -------------------------------

// x1t[row][col] = silu(bn1( sum_d xt[row][d] * w1b[col][d] ))
__global__ __launch_bounds__(256) void gemm1_kernel(
    const bf16* __restrict__ xt, const bf16* __restrict__ w1b,
    const float* __restrict__ bn1s, const float* __restrict__ bn1h,
    bf16* __restrict__ x1t)
{
    const bf16* A = xt + (size_t)(blockIdx.y * 128) * 512;
    const bf16* Bm = w1b + (size_t)(blockIdx.x * 128) * 512;
    f32x4 acc[4][4];
    gemm_core_lds(A, 512, Bm, 512, 512, acc);
    int wave = threadIdx.x >> 6;
    int lane = threadIdx.x & 63;
    int m0 = blockIdx.y * 128 + (wave >> 1) * 64;
    int n0 = blockIdx.x * 128 + (wave & 1) * 64;
    int lm = lane & 15, kq = lane >> 4;
#pragma unroll
    for (int i = 0; i < 4; ++i)
#pragma unroll
        for (int j = 0; j < 4; ++j)
#pragma unroll
            for (int r = 0; r < 4; ++r) {
                int row = m0 + i * 16 + kq * 4 + r;
                int col = n0 + j * 16 + lm;
                float h = bn1s[col] * acc[i][j][r] + bn1h[col];
                x1t[(size_t)row * 256 + col] = (bf16)silu_f(h);
            }
}

// projections: col<512 -> qk[.][col]; <768 -> v_nm[.][col-512]; else e_nm
__global__ __launch_bounds__(256) void gemm2_kernel(
    const bf16* __restrict__ x1t, const bf16* __restrict__ wqkve,
    const float* __restrict__ biasq,
    bf16* __restrict__ qk, bf16* __restrict__ v_nm, bf16* __restrict__ e_nm)
{
    const bf16* A = x1t + (size_t)(blockIdx.y * 128) * 256;
    const bf16* Bm = wqkve + (size_t)(blockIdx.x * 128) * 256;
    f32x4 acc[4][4];
    gemm_core_lds(A, 256, Bm, 256, 256, acc);
    int wave = threadIdx.x >> 6;
    int lane = threadIdx.x & 63;
    int m0 = blockIdx.y * 128 + (wave >> 1) * 64;
    int n0 = blockIdx.x * 128 + (wave & 1) * 64;
    int lm = lane & 15, kq = lane >> 4;
#pragma unroll
    for (int i = 0; i < 4; ++i)
#pragma unroll
        for (int j = 0; j < 4; ++j)
#pragma unroll
            for (int r = 0; r < 4; ++r) {
                int row = m0 + i * 16 + kq * 4 + r;
                int col = n0 + j * 16 + lm;
                bf16 val = (bf16)(acc[i][j][r] + biasq[col]);
                if (col < 512)       qk[(size_t)row * 512 + col] = val;
                else if (col < 768)  v_nm[(size_t)row * 256 + (col - 512)] = val;
                else                 e_nm[(size_t)row * 256 + (col - 768)] = val;
            }
}

// rhw[b][r][m] = sum_c posT[r][c] * e_nm[b*4096+m][c]   (r<64: RH, r>=64: RW)
__global__ __launch_bounds__(256) void gemm_rhw_kernel(
    const bf16* __restrict__ posT, const bf16* __restrict__ e_nm,
    bf16* __restrict__ rhw)
{
    int b = blockIdx.z;
    const bf16* Bm = e_nm + ((size_t)b * 4096 + blockIdx.x * 128) * 256;
    f32x4 acc[4][4];
    gemm_core_lds(posT, 256, Bm, 256, 256, acc);
    int wave = threadIdx.x >> 6;
    int lane = threadIdx.x & 63;
    int m0 = (wave >> 1) * 64, n0 = (wave & 1) * 64;
    int lm = lane & 15, kq = lane >> 4;
    bf16* rb = rhw + (size_t)b * 128 * 4096 + blockIdx.x * 128;
#pragma unroll
    for (int i = 0; i < 4; ++i)
#pragma unroll
        for (int j = 0; j < 4; ++j)
#pragma unroll
            for (int r = 0; r < 4; ++r)
                rb[(size_t)(m0 + i * 16 + kq * 4 + r) * 4096 + n0 + j * 16 + lm] =
                    (bf16)acc[i][j][r];
}

// P[bz][n][m] = exp(q[b,n,:].k[b,m,:] + RH[h_n,m] + RW[w_n,m] - 8), bf16;
// row sums -> lsum[bz][n]
__global__ __launch_bounds__(256) void gemm3b_kernel(
    const bf16* __restrict__ qk, const bf16* __restrict__ rhw,
    bf16* __restrict__ P, float* __restrict__ lsum, int gbase)
{
    __shared__ float rs[128];
    __shared__ bf16 rhw_h[2][132];
    __shared__ bf16 rhw_w[64][132];
    // XCD-aware bijective swizzle (4096 blocks, %8==0): each XCD gets a
    // contiguous 512-block chunk -> ~3MB of qk, fits per-XCD 4MB L2.
    int flat = blockIdx.x + 32 * blockIdx.y + 1024 * blockIdx.z;
    flat = (flat & 7) * 512 + (flat >> 3);
    const int bx = flat & 31, by = (flat >> 5) & 31, bz = flat >> 10;
    const int b = gbase + bz;
    // stage RHW slices: 2 h-rows for this y-block + all 64 w-rows, cols bx*128..
    {
        const bf16* rbase = rhw + ((size_t)b * 128) * 4096 + bx * 128;
        for (int t = threadIdx.x; t < 66 * 128; t += 256) {
            int rr = t >> 7, c = t & 127;
            if (rr < 2) rhw_h[rr][c] = rbase[(size_t)(by * 2 + rr) * 4096 + c];
            else        rhw_w[rr - 2][c] = rbase[(size_t)(62 + rr) * 4096 + c];
        }
    }
    const bf16* A = qk + ((size_t)b * 4096 + by * 128) * 512;
    const bf16* Bm = qk + ((size_t)b * 4096 + bx * 128) * 512 + 256;
    f32x4 acc[4][4];
    gemm_core_lds(A, 512, Bm, 512, 256, acc);
    int tid = threadIdx.x;
    int wave = tid >> 6;
    int lane = tid & 63;
    int m0 = (wave >> 1) * 64, n0 = (wave & 1) * 64;
    int lm = lane & 15, kq = lane >> 4;
    if (tid < 128) rs[tid] = 0.f;
    __syncthreads();
    // add positional terms, exp, per-lane row partials
    float ps[4][4];
#pragma unroll
    for (int i = 0; i < 4; ++i)
#pragma unroll
        for (int r = 0; r < 4; ++r) {
            int lr = m0 + i * 16 + kq * 4 + r;
            float s = 0.f;
#pragma unroll
            for (int j = 0; j < 4; ++j) {
                int lc = n0 + j * 16 + lm;
                float sv = acc[i][j][r] + (float)rhw_h[lr >> 6][lc]
                                        + (float)rhw_w[lr & 63][lc];
                float e = __expf(sv - 8.f);
                acc[i][j][r] = e;
                s += e;
            }
            ps[i][r] = s;
        }
    // butterfly over the 16-lane lm group (covers the wave's 64 cols)
#pragma unroll
    for (int msk = 1; msk < 16; msk <<= 1)
#pragma unroll
        for (int i = 0; i < 4; ++i)
#pragma unroll
            for (int r = 0; r < 4; ++r)
                ps[i][r] += __shfl_xor(ps[i][r], msk);
    if (lm == 0) {
#pragma unroll
        for (int i = 0; i < 4; ++i)
#pragma unroll
            for (int r = 0; r < 4; ++r)
                atomicAdd(&rs[m0 + i * 16 + kq * 4 + r], ps[i][r]);
    }
    // store exp(S) tile
    bf16* Pb = P + ((size_t)bz * 4096 + by * 128) * 4096 + bx * 128;
#pragma unroll
    for (int i = 0; i < 4; ++i)
#pragma unroll
        for (int j = 0; j < 4; ++j)
#pragma unroll
            for (int r = 0; r < 4; ++r)
                Pb[(size_t)(m0 + i * 16 + kq * 4 + r) * 4096 + n0 + j * 16 + lm] =
                    (bf16)acc[i][j][r];
    __syncthreads();
    if (tid < 128)
        atomicAdd(&lsum[(size_t)bz * 4096 + by * 128 + tid], rs[tid]);
}

// out_t[(gbase+bz)*4096+n][c] = (1/lsum[bz][n]) * sum_m P[bz][n][m]*v_cm[b][c][m]
__global__ __launch_bounds__(256) void gemm4b_kernel(
    const bf16* __restrict__ P, const bf16* __restrict__ v_cm,
    const float* __restrict__ lsum,
    bf16* __restrict__ out_t, int gbase)
{
    int bz = blockIdx.z;
    int b = gbase + bz;
    const bf16* A = P + ((size_t)bz * 4096 + blockIdx.y * 128) * 4096;
    const bf16* Bm = v_cm + ((size_t)b * 256 + blockIdx.x * 128) * 4096;
    f32x4 acc[4][4];
    gemm_core_lds(A, 4096, Bm, 4096, 4096, acc);
    int wave = threadIdx.x >> 6;
    int lane = threadIdx.x & 63;
    int m0 = (wave >> 1) * 64, n0 = (wave & 1) * 64;
    int lm = lane & 15, kq = lane >> 4;
    const float* ls = lsum + (size_t)bz * 4096 + blockIdx.y * 128;
    bf16* ob = out_t + ((size_t)b * 4096 + blockIdx.y * 128) * 256 + blockIdx.x * 128;
#pragma unroll
    for (int i = 0; i < 4; ++i)
#pragma unroll
        for (int r = 0; r < 4; ++r) {
            float inv = 1.f / ls[m0 + i * 16 + kq * 4 + r];
#pragma unroll
            for (int j = 0; j < 4; ++j)
                ob[(size_t)(m0 + i * 16 + kq * 4 + r) * 256 + n0 + j * 16 + lm] =
                    (bf16)(acc[i][j][r] * inv);
        }
}

// d_out[b][d][n] = x[b][d][n] + silu(bn2( sum_c w2b[d][c]*out_t[b*4096+n][c] ))
__global__ __launch_bounds__(256) void gemm5_kernel(
    const bf16* __restrict__ w2b, const bf16* __restrict__ out_t,
    const float* __restrict__ bn2s, const float* __restrict__ bn2h,
    const float* __restrict__ x, float* __restrict__ out)
{
    int b = blockIdx.z;
    const bf16* A = w2b + (size_t)(blockIdx.y * 128) * 256;
    const bf16* Bm = out_t + ((size_t)b * 4096 + blockIdx.x * 128) * 256;
    f32x4 acc[4][4];
    gemm_core_lds(A, 256, Bm, 256, 256, acc);
    int wave = threadIdx.x >> 6;
    int lane = threadIdx.x & 63;
    int m0 = blockIdx.y * 128 + (wave >> 1) * 64;   // d (512)
    int n0 = blockIdx.x * 128 + (wave & 1) * 64;    // n (4096)
    int lm = lane & 15, kq = lane >> 4;
#pragma unroll
    for (int i = 0; i < 4; ++i)
#pragma unroll
        for (int j = 0; j < 4; ++j)
#pragma unroll
            for (int r = 0; r < 4; ++r) {
                int d = m0 + i * 16 + kq * 4 + r;
                int n = n0 + j * 16 + lm;
                float h = bn2s[d] * acc[i][j][r] + bn2h[d];
                size_t gi = ((size_t)(b * 512 + d)) * 4096 + n;
                out[gi] = x[gi] + silu_f(h);
            }
}

// ------------------------------- launcher ----------------------------------

extern "C" void kernel_launch(void* const* d_in, const int* in_sizes, int n_in,
                              void* d_out, int out_size, void* d_ws, size_t ws_size,
                              hipStream_t stream)
{
    (void)in_sizes; (void)n_in; (void)out_size; (void)ws_size;
    const float* x     = (const float*)d_in[0];
    const float* cv1_w = (const float*)d_in[1];
    const float* bn1_g = (const float*)d_in[2];
    const float* bn1_b = (const float*)d_in[3];
    const float* bn1_m = (const float*)d_in[4];
    const float* bn1_v = (const float*)d_in[5];
    const float* q_w   = (const float*)d_in[6];
    const float* q_b   = (const float*)d_in[7];
    const float* k_w   = (const float*)d_in[8];
    const float* k_b   = (const float*)d_in[9];
    const float* v_w   = (const float*)d_in[10];
    const float* v_b   = (const float*)d_in[11];
    const float* e_w   = (const float*)d_in[12];
    const float* e_b   = (const float*)d_in[13];
    const float* rel_h = (const float*)d_in[14];
    const float* rel_w = (const float*)d_in[15];
    const float* cv2_w = (const float*)d_in[16];
    const float* bn2_g = (const float*)d_in[17];
    const float* bn2_b = (const float*)d_in[18];
    const float* bn2_m = (const float*)d_in[19];
    const float* bn2_v = (const float*)d_in[20];
    float* out = (float*)d_out;

    char* ws = (char*)d_ws;
    // P_grp region (128 MB) also hosts xt/x1t/v_nm/e_nm (dead before attention)
    bf16* P     = (bf16*)(ws + 0);            // 128 MB [4][4096][4096]
    bf16* xt    = (bf16*)(ws + 0);            //  32 MB overlay
    bf16* x1t   = (bf16*)(ws + 33554432);     //  16 MB overlay
    bf16* v_nm  = (bf16*)(ws + 50331648);     //  16 MB overlay
    bf16* e_nm  = (bf16*)(ws + 67108864);     //  16 MB overlay
    bf16* qk    = (bf16*)(ws + 134217728);    //  32 MB [32768][512] (q|k)
    bf16* v_cm  = (bf16*)(ws + 167772160);    //  16 MB [8][256][4096]
    bf16* rhw   = (bf16*)(ws + 184549376);    //   8 MB [8][128][4096]
    bf16* out_t = (bf16*)(ws + 192937984);    //  16 MB [32768][256]
    bf16* w1b   = (bf16*)(ws + 209715200);    // 256 KB
    bf16* wqkve = (bf16*)(ws + 209977344);    // 512 KB
    bf16* w2b   = (bf16*)(ws + 210501632);    // 256 KB
    bf16* posT  = (bf16*)(ws + 210763776);    //  64 KB [128][256]
    float* biasq= (float*)(ws + 210829312);   //   4 KB
    float* bn1s = (float*)(ws + 210833408);
    float* bn1h = (float*)(ws + 210834432);
    float* bn2s = (float*)(ws + 210835456);
    float* bn2h = (float*)(ws + 210837504);
    float* lsum = (float*)(ws + 210839552);   // 128 KB [2][4][4096] fp32

    prep_misc_kernel<<<2183, 256, 0, stream>>>(
        cv1_w, q_w, q_b, k_w, k_b, v_w, v_b, e_w, e_b, cv2_w,
        bn1_g, bn1_b, bn1_m, bn1_v, bn2_g, bn2_b, bn2_m, bn2_v,
        rel_h, rel_w,
        w1b, wqkve, w2b, posT, biasq, bn1s, bn1h, bn2s, bn2h);
    zero_lsum_kernel<<<128, 256, 0, stream>>>(lsum);
    transpose_x_kernel<<<dim3(64, 8, 8), 256, 0, stream>>>(x, xt);
    gemm1_kernel<<<dim3(2, 256), 256, 0, stream>>>(xt, w1b, bn1s, bn1h, x1t);
    gemm2_kernel<<<dim3(8, 256), 256, 0, stream>>>(x1t, wqkve, biasq, qk, v_nm, e_nm);
    gemm_rhw_kernel<<<dim3(32, 1, 8), 256, 0, stream>>>(posT, e_nm, rhw);
    transpose_v_kernel<<<dim3(64, 4, 8), 256, 0, stream>>>(v_nm, v_cm);
    for (int g = 0; g < 2; ++g) {
        float* ls = lsum + (size_t)g * 4 * 4096;
        gemm3b_kernel<<<dim3(32, 32, 4), 256, 0, stream>>>(qk, rhw, P, ls, g * 4);
        gemm4b_kernel<<<dim3(2, 32, 4), 256, 0, stream>>>(P, v_cm, ls, out_t, g * 4);
    }
    gemm5_kernel<<<dim3(32, 4, 8), 256, 0, stream>>>(w2b, out_t, bn2s, bn2h, x, out);
}

// Round 2
// 676.782 us; speedup vs baseline: 1.0582x; 1.0582x over previous
//
#include <hip/hip_runtime.h>

// ---------------------------------------------------------------------------
// ExtraPositionPromptSABottleneck on MI355X (gfx950)
// B=8, DIMS=512, C=256, H=W=64, N=4096.
//
// Round 6:
//  - Keep round-5 algebraic factorization (pos -> RH/RW, gemm3b K=256) but
//    fix its overhead: positional table stored transposed rhwT[b][m][128]
//    (r<64 = RH[h][m], r>=64 = RW[w][m]).  gemm3b loads its pos terms as
//    ~20 vectorized register loads per thread (1 scalar + 4x bf16x4 per
//    column) issued BEFORE the GEMM core, so K-loop hides the latency.
//  - No extra LDS (back to 16.9 KB -> round-4 occupancy), no serial staging
//    phase, epilogue pos-add is register-only.
// ---------------------------------------------------------------------------

typedef __bf16 bf16;
typedef __attribute__((ext_vector_type(8))) __bf16 bf16x8;
typedef __attribute__((ext_vector_type(4))) __bf16 bf16x4;
typedef __attribute__((ext_vector_type(4))) float f32x4;

__device__ __forceinline__ float silu_f(float x) { return x / (1.f + __expf(-x)); }

__device__ __forceinline__ void zero_acc(f32x4 (&acc)[4][4])
{
#pragma unroll
    for (int i = 0; i < 4; ++i)
#pragma unroll
        for (int j = 0; j < 4; ++j)
            acc[i][j] = (f32x4){0.f, 0.f, 0.f, 0.f};
}

// ---- LDS-staged GEMM core: block 256 thr, tile 128x128, BK=32
__device__ __forceinline__ void load_lds16(const bf16* g, bf16* l)
{
    __builtin_amdgcn_global_load_lds(
        (const __attribute__((address_space(1))) unsigned int*)g,
        (__attribute__((address_space(3))) unsigned int*)l, 16, 0, 0);
}

// A: block's 128 rows, k-contig stride lda. B: block's 128 "cols", stride ldb.
// LDS slot (row, kb) holds global (row, kb ^ ((row>>1)&3)) -- XOR swizzle.
__device__ __forceinline__ void gemm_core_lds(
    const bf16* __restrict__ A, int lda,
    const bf16* __restrict__ B, int ldb,
    int K, f32x4 (&acc)[4][4])
{
    __shared__ bf16 As[128 * 32];
    __shared__ bf16 Bs[128 * 32];
    const int tid = threadIdx.x;
    const int wave = tid >> 6;
    const int lane = tid & 63;
    const int lm = lane & 15;
    const int kq = lane >> 4;
    const int m0 = (wave >> 1) * 64;
    const int n0 = (wave & 1) * 64;
    // staging: each thread supplies 16B per round; 2 rounds per matrix.
    const int srow = tid >> 2;                              // rows 0..63, +64
    const int skoff = (((tid & 3) ^ ((tid >> 3) & 3))) * 8; // swizzled k-block
    const int krd = (kq ^ ((lm >> 1) & 3)) * 8;             // read-side offset
    bf16* lA = As + tid * 8;            // LDS dest = wave_base + lane*16B
    bf16* lB = Bs + tid * 8;
    zero_acc(acc);
    for (int k0 = 0; k0 < K; k0 += 32) {
        const bf16* ga = A + (size_t)srow * lda + k0 + skoff;
        const bf16* gb = B + (size_t)srow * ldb + k0 + skoff;
        load_lds16(ga, lA);
        load_lds16(ga + (size_t)64 * lda, lA + 64 * 32);
        load_lds16(gb, lB);
        load_lds16(gb + (size_t)64 * ldb, lB + 64 * 32);
        __syncthreads();
        bf16x8 av[4], bv[4];
#pragma unroll
        for (int t = 0; t < 4; ++t)
            av[t] = *(const bf16x8*)(As + (m0 + t * 16 + lm) * 32 + krd);
#pragma unroll
        for (int t = 0; t < 4; ++t)
            bv[t] = *(const bf16x8*)(Bs + (n0 + t * 16 + lm) * 32 + krd);
#pragma unroll
        for (int i = 0; i < 4; ++i)
#pragma unroll
            for (int j = 0; j < 4; ++j)
                acc[i][j] = __builtin_amdgcn_mfma_f32_16x16x32_bf16(
                    av[i], bv[j], acc[i][j], 0, 0, 0);
        __syncthreads();
    }
}

// ------------------------------ prep kernels -------------------------------

__global__ __launch_bounds__(256) void prep_misc_kernel(
    const float* __restrict__ cv1_w,
    const float* __restrict__ qw, const float* __restrict__ qb,
    const float* __restrict__ kw, const float* __restrict__ kb,
    const float* __restrict__ vw, const float* __restrict__ vb,
    const float* __restrict__ ew, const float* __restrict__ eb,
    const float* __restrict__ cv2_w,
    const float* __restrict__ g1, const float* __restrict__ b1,
    const float* __restrict__ m1, const float* __restrict__ v1,
    const float* __restrict__ g2, const float* __restrict__ b2,
    const float* __restrict__ m2, const float* __restrict__ v2,
    const float* __restrict__ rel_h, const float* __restrict__ rel_w,
    bf16* __restrict__ w1b, bf16* __restrict__ wqkve, bf16* __restrict__ w2b,
    bf16* __restrict__ posT,
    float* __restrict__ biasq,
    float* __restrict__ bn1s, float* __restrict__ bn1h,
    float* __restrict__ bn2s, float* __restrict__ bn2h)
{
    int idx = blockIdx.x * 256 + threadIdx.x;
    if (idx < 131072) { w1b[idx] = (bf16)cv1_w[idx]; return; }
    idx -= 131072;
    if (idx < 262144) {
        int j = idx >> 8, c = idx & 255;
        int p = j >> 8, r = j & 255;
        const float* w = (p == 0) ? qw : (p == 1) ? kw : (p == 2) ? vw : ew;
        wqkve[idx] = (bf16)w[r * 256 + c];
        return;
    }
    idx -= 262144;
    if (idx < 131072) { w2b[idx] = (bf16)cv2_w[idx]; return; }
    idx -= 131072;
    if (idx < 1024) {
        int p = idx >> 8, r = idx & 255;
        const float* bb = (p == 0) ? qb : (p == 1) ? kb : (p == 2) ? vb : eb;
        biasq[idx] = bb[r];
        return;
    }
    idx -= 1024;
    if (idx < 256) {
        float s = g1[idx] * rsqrtf(v1[idx] + 1e-5f);
        bn1s[idx] = s;
        bn1h[idx] = b1[idx] - m1[idx] * s;
        return;
    }
    idx -= 256;
    if (idx < 512) {
        float s = g2[idx] * rsqrtf(v2[idx] + 1e-5f);
        bn2s[idx] = s;
        bn2h[idx] = b2[idx] - m2[idx] * s;
        return;
    }
    idx -= 512;
    if (idx < 32768) {
        // posT[r][c], r<64: rel_h[c][r]; r>=64: rel_w[c][r-64]
        int r = idx >> 8, c = idx & 255;
        posT[idx] = (bf16)((r < 64) ? rel_h[c * 64 + r] : rel_w[c * 64 + (r - 64)]);
        return;
    }
}

__global__ __launch_bounds__(256) void zero_lsum_kernel(float* __restrict__ p)
{
    p[blockIdx.x * 256 + threadIdx.x] = 0.f;
}

// xt[b*4096+n][d] = (bf16) x[b][d][n]
__global__ __launch_bounds__(256) void transpose_x_kernel(
    const float* __restrict__ x, bf16* __restrict__ xt)
{
    __shared__ float tile[64][65];
    int b = blockIdx.z;
    int n0 = blockIdx.x * 64;
    int d0 = blockIdx.y * 64;
    int tx = threadIdx.x & 63, ty = threadIdx.x >> 6;
#pragma unroll
    for (int i = 0; i < 16; ++i) {
        int d = i * 4 + ty;
        tile[d][tx] = x[((size_t)(b * 512 + d0 + d)) * 4096 + n0 + tx];
    }
    __syncthreads();
#pragma unroll
    for (int i = 0; i < 16; ++i) {
        int n = i * 4 + ty;
        xt[((size_t)(b * 4096 + n0 + n)) * 512 + d0 + tx] = (bf16)tile[tx][n];
    }
}

// v_cm[b][c][m] = v_nm[b*4096+m][c]
__global__ __launch_bounds__(256) void transpose_v_kernel(
    const bf16* __restrict__ v_nm, bf16* __restrict__ v_cm)
{
    __shared__ float tile[64][65];
    int b = blockIdx.z;
    int m0 = blockIdx.x * 64;
    int c0 = blockIdx.y * 64;
    int tx = threadIdx.x & 63, ty = threadIdx.x >> 6;
#pragma unroll
    for (int i = 0; i < 16; ++i) {
        int m = i * 4 + ty;
        tile[m][tx] = (float)v_nm[((size_t)(b * 4096 + m0 + m)) * 256 + c0 + tx];
    }
    __syncthreads();
#pragma unroll
    for (int i = 0; i < 16; ++i) {
        int c = i * 4 + ty;
        v_cm[((size_t)(b * 256 + c0 + c)) * 4096 + m0 + tx] = (bf16)tile[tx][c];
    }
}

// ------------------------------ GEMM kernels -------------------------------

// x1t[row][col] = silu(bn1( sum_d xt[row][d] * w1b[col][d] ))
__global__ __launch_bounds__(256) void gemm1_kernel(
    const bf16* __restrict__ xt, const bf16* __restrict__ w1b,
    const float* __restrict__ bn1s, const float* __restrict__ bn1h,
    bf16* __restrict__ x1t)
{
    const bf16* A = xt + (size_t)(blockIdx.y * 128) * 512;
    const bf16* Bm = w1b + (size_t)(blockIdx.x * 128) * 512;
    f32x4 acc[4][4];
    gemm_core_lds(A, 512, Bm, 512, 512, acc);
    int wave = threadIdx.x >> 6;
    int lane = threadIdx.x & 63;
    int m0 = blockIdx.y * 128 + (wave >> 1) * 64;
    int n0 = blockIdx.x * 128 + (wave & 1) * 64;
    int lm = lane & 15, kq = lane >> 4;
#pragma unroll
    for (int i = 0; i < 4; ++i)
#pragma unroll
        for (int j = 0; j < 4; ++j)
#pragma unroll
            for (int r = 0; r < 4; ++r) {
                int row = m0 + i * 16 + kq * 4 + r;
                int col = n0 + j * 16 + lm;
                float h = bn1s[col] * acc[i][j][r] + bn1h[col];
                x1t[(size_t)row * 256 + col] = (bf16)silu_f(h);
            }
}

// projections: col<512 -> qk[.][col]; <768 -> v_nm[.][col-512]; else e_nm
__global__ __launch_bounds__(256) void gemm2_kernel(
    const bf16* __restrict__ x1t, const bf16* __restrict__ wqkve,
    const float* __restrict__ biasq,
    bf16* __restrict__ qk, bf16* __restrict__ v_nm, bf16* __restrict__ e_nm)
{
    const bf16* A = x1t + (size_t)(blockIdx.y * 128) * 256;
    const bf16* Bm = wqkve + (size_t)(blockIdx.x * 128) * 256;
    f32x4 acc[4][4];
    gemm_core_lds(A, 256, Bm, 256, 256, acc);
    int wave = threadIdx.x >> 6;
    int lane = threadIdx.x & 63;
    int m0 = blockIdx.y * 128 + (wave >> 1) * 64;
    int n0 = blockIdx.x * 128 + (wave & 1) * 64;
    int lm = lane & 15, kq = lane >> 4;
#pragma unroll
    for (int i = 0; i < 4; ++i)
#pragma unroll
        for (int j = 0; j < 4; ++j)
#pragma unroll
            for (int r = 0; r < 4; ++r) {
                int row = m0 + i * 16 + kq * 4 + r;
                int col = n0 + j * 16 + lm;
                bf16 val = (bf16)(acc[i][j][r] + biasq[col]);
                if (col < 512)       qk[(size_t)row * 512 + col] = val;
                else if (col < 768)  v_nm[(size_t)row * 256 + (col - 512)] = val;
                else                 e_nm[(size_t)row * 256 + (col - 768)] = val;
            }
}

// rhwT[b][m][r] = sum_c posT[r][c] * e_nm[b*4096+m][c]  (r<64: RH, r>=64: RW)
// A = e-rows (m), B = posT rows (r): acc rows = m-local, cols = r.
__global__ __launch_bounds__(256) void gemm_rhw_kernel(
    const bf16* __restrict__ posT, const bf16* __restrict__ e_nm,
    bf16* __restrict__ rhwT)
{
    int b = blockIdx.z;
    const bf16* A = e_nm + ((size_t)b * 4096 + blockIdx.x * 128) * 256;
    f32x4 acc[4][4];
    gemm_core_lds(A, 256, posT, 256, 256, acc);
    int wave = threadIdx.x >> 6;
    int lane = threadIdx.x & 63;
    int m0 = (wave >> 1) * 64, n0 = (wave & 1) * 64;
    int lm = lane & 15, kq = lane >> 4;
    bf16* rb = rhwT + ((size_t)b * 4096 + blockIdx.x * 128) * 128;
#pragma unroll
    for (int i = 0; i < 4; ++i)
#pragma unroll
        for (int j = 0; j < 4; ++j)
#pragma unroll
            for (int r = 0; r < 4; ++r)
                rb[(size_t)(m0 + i * 16 + kq * 4 + r) * 128 + n0 + j * 16 + lm] =
                    (bf16)acc[i][j][r];
}

// P[bz][n][m] = exp(q[b,n,:].k[b,m,:] + RH[h_n,m] + RW[w_n,m] - 8), bf16;
// row sums -> lsum[bz][n]
__global__ __launch_bounds__(256) void gemm3b_kernel(
    const bf16* __restrict__ qk, const bf16* __restrict__ rhwT,
    bf16* __restrict__ P, float* __restrict__ lsum, int gbase)
{
    __shared__ float rs[128];
    // XCD-aware bijective swizzle (4096 blocks, %8==0): each XCD gets a
    // contiguous 512-block chunk -> qk slice fits per-XCD 4MB L2.
    int flat = blockIdx.x + 32 * blockIdx.y + 1024 * blockIdx.z;
    flat = (flat & 7) * 512 + (flat >> 3);
    const int bx = flat & 31, by = (flat >> 5) & 31, bz = flat >> 10;
    const int b = gbase + bz;
    const int tid = threadIdx.x;
    const int wave = tid >> 6;
    const int lane = tid & 63;
    const int m0 = (wave >> 1) * 64, n0 = (wave & 1) * 64;
    const int lm = lane & 15, kq = lane >> 4;
    // ---- positional terms -> registers (L2-hot, vectorized), issued early
    // so the K-loop hides their latency.  This thread's 16 rows share one
    // h-index (2*by + wave>>1); row&63 = i*16 + kq*4 + r (4 aligned chunks).
    float rhv[4];
    bf16x4 rwv[4][4]; // [j][i]
    {
        const bf16* rbT = rhwT + ((size_t)b * 4096 + bx * 128) * 128;
        const int hidx = 2 * by + (m0 >> 6);
#pragma unroll
        for (int j = 0; j < 4; ++j) {
            const bf16* cp = rbT + (size_t)(n0 + j * 16 + lm) * 128;
            rhv[j] = (float)cp[hidx];
#pragma unroll
            for (int i = 0; i < 4; ++i)
                rwv[j][i] = *(const bf16x4*)(cp + 64 + i * 16 + kq * 4);
        }
    }
    const bf16* A = qk + ((size_t)b * 4096 + by * 128) * 512;
    const bf16* Bm = qk + ((size_t)b * 4096 + bx * 128) * 512 + 256;
    f32x4 acc[4][4];
    gemm_core_lds(A, 512, Bm, 512, 256, acc);
    if (tid < 128) rs[tid] = 0.f;
    __syncthreads();
    // add positional terms, exp, per-lane row partials
    float ps[4][4];
#pragma unroll
    for (int i = 0; i < 4; ++i)
#pragma unroll
        for (int r = 0; r < 4; ++r) {
            float s = 0.f;
#pragma unroll
            for (int j = 0; j < 4; ++j) {
                float sv = acc[i][j][r] + rhv[j] + (float)rwv[j][i][r];
                float e = __expf(sv - 8.f);
                acc[i][j][r] = e;
                s += e;
            }
            ps[i][r] = s;
        }
    // butterfly over the 16-lane lm group (covers the wave's 64 cols)
#pragma unroll
    for (int msk = 1; msk < 16; msk <<= 1)
#pragma unroll
        for (int i = 0; i < 4; ++i)
#pragma unroll
            for (int r = 0; r < 4; ++r)
                ps[i][r] += __shfl_xor(ps[i][r], msk);
    if (lm == 0) {
#pragma unroll
        for (int i = 0; i < 4; ++i)
#pragma unroll
            for (int r = 0; r < 4; ++r)
                atomicAdd(&rs[m0 + i * 16 + kq * 4 + r], ps[i][r]);
    }
    // store exp(S) tile
    bf16* Pb = P + ((size_t)bz * 4096 + by * 128) * 4096 + bx * 128;
#pragma unroll
    for (int i = 0; i < 4; ++i)
#pragma unroll
        for (int j = 0; j < 4; ++j)
#pragma unroll
            for (int r = 0; r < 4; ++r)
                Pb[(size_t)(m0 + i * 16 + kq * 4 + r) * 4096 + n0 + j * 16 + lm] =
                    (bf16)acc[i][j][r];
    __syncthreads();
    if (tid < 128)
        atomicAdd(&lsum[(size_t)bz * 4096 + by * 128 + tid], rs[tid]);
}

// out_t[(gbase+bz)*4096+n][c] = (1/lsum[bz][n]) * sum_m P[bz][n][m]*v_cm[b][c][m]
__global__ __launch_bounds__(256) void gemm4b_kernel(
    const bf16* __restrict__ P, const bf16* __restrict__ v_cm,
    const float* __restrict__ lsum,
    bf16* __restrict__ out_t, int gbase)
{
    int bz = blockIdx.z;
    int b = gbase + bz;
    const bf16* A = P + ((size_t)bz * 4096 + blockIdx.y * 128) * 4096;
    const bf16* Bm = v_cm + ((size_t)b * 256 + blockIdx.x * 128) * 4096;
    f32x4 acc[4][4];
    gemm_core_lds(A, 4096, Bm, 4096, 4096, acc);
    int wave = threadIdx.x >> 6;
    int lane = threadIdx.x & 63;
    int m0 = (wave >> 1) * 64, n0 = (wave & 1) * 64;
    int lm = lane & 15, kq = lane >> 4;
    const float* ls = lsum + (size_t)bz * 4096 + blockIdx.y * 128;
    bf16* ob = out_t + ((size_t)b * 4096 + blockIdx.y * 128) * 256 + blockIdx.x * 128;
#pragma unroll
    for (int i = 0; i < 4; ++i)
#pragma unroll
        for (int r = 0; r < 4; ++r) {
            float inv = 1.f / ls[m0 + i * 16 + kq * 4 + r];
#pragma unroll
            for (int j = 0; j < 4; ++j)
                ob[(size_t)(m0 + i * 16 + kq * 4 + r) * 256 + n0 + j * 16 + lm] =
                    (bf16)(acc[i][j][r] * inv);
        }
}

// d_out[b][d][n] = x[b][d][n] + silu(bn2( sum_c w2b[d][c]*out_t[b*4096+n][c] ))
__global__ __launch_bounds__(256) void gemm5_kernel(
    const bf16* __restrict__ w2b, const bf16* __restrict__ out_t,
    const float* __restrict__ bn2s, const float* __restrict__ bn2h,
    const float* __restrict__ x, float* __restrict__ out)
{
    int b = blockIdx.z;
    const bf16* A = w2b + (size_t)(blockIdx.y * 128) * 256;
    const bf16* Bm = out_t + ((size_t)b * 4096 + blockIdx.x * 128) * 256;
    f32x4 acc[4][4];
    gemm_core_lds(A, 256, Bm, 256, 256, acc);
    int wave = threadIdx.x >> 6;
    int lane = threadIdx.x & 63;
    int m0 = blockIdx.y * 128 + (wave >> 1) * 64;   // d (512)
    int n0 = blockIdx.x * 128 + (wave & 1) * 64;    // n (4096)
    int lm = lane & 15, kq = lane >> 4;
#pragma unroll
    for (int i = 0; i < 4; ++i)
#pragma unroll
        for (int j = 0; j < 4; ++j)
#pragma unroll
            for (int r = 0; r < 4; ++r) {
                int d = m0 + i * 16 + kq * 4 + r;
                int n = n0 + j * 16 + lm;
                float h = bn2s[d] * acc[i][j][r] + bn2h[d];
                size_t gi = ((size_t)(b * 512 + d)) * 4096 + n;
                out[gi] = x[gi] + silu_f(h);
            }
}

// ------------------------------- launcher ----------------------------------

extern "C" void kernel_launch(void* const* d_in, const int* in_sizes, int n_in,
                              void* d_out, int out_size, void* d_ws, size_t ws_size,
                              hipStream_t stream)
{
    (void)in_sizes; (void)n_in; (void)out_size; (void)ws_size;
    const float* x     = (const float*)d_in[0];
    const float* cv1_w = (const float*)d_in[1];
    const float* bn1_g = (const float*)d_in[2];
    const float* bn1_b = (const float*)d_in[3];
    const float* bn1_m = (const float*)d_in[4];
    const float* bn1_v = (const float*)d_in[5];
    const float* q_w   = (const float*)d_in[6];
    const float* q_b   = (const float*)d_in[7];
    const float* k_w   = (const float*)d_in[8];
    const float* k_b   = (const float*)d_in[9];
    const float* v_w   = (const float*)d_in[10];
    const float* v_b   = (const float*)d_in[11];
    const float* e_w   = (const float*)d_in[12];
    const float* e_b   = (const float*)d_in[13];
    const float* rel_h = (const float*)d_in[14];
    const float* rel_w = (const float*)d_in[15];
    const float* cv2_w = (const float*)d_in[16];
    const float* bn2_g = (const float*)d_in[17];
    const float* bn2_b = (const float*)d_in[18];
    const float* bn2_m = (const float*)d_in[19];
    const float* bn2_v = (const float*)d_in[20];
    float* out = (float*)d_out;

    char* ws = (char*)d_ws;
    // P_grp region (128 MB) also hosts xt/x1t/v_nm/e_nm (dead before attention)
    bf16* P     = (bf16*)(ws + 0);            // 128 MB [4][4096][4096]
    bf16* xt    = (bf16*)(ws + 0);            //  32 MB overlay
    bf16* x1t   = (bf16*)(ws + 33554432);     //  16 MB overlay
    bf16* v_nm  = (bf16*)(ws + 50331648);     //  16 MB overlay
    bf16* e_nm  = (bf16*)(ws + 67108864);     //  16 MB overlay
    bf16* qk    = (bf16*)(ws + 134217728);    //  32 MB [32768][512] (q|k)
    bf16* v_cm  = (bf16*)(ws + 167772160);    //  16 MB [8][256][4096]
    bf16* rhwT  = (bf16*)(ws + 184549376);    //   8 MB [8][4096][128]
    bf16* out_t = (bf16*)(ws + 192937984);    //  16 MB [32768][256]
    bf16* w1b   = (bf16*)(ws + 209715200);    // 256 KB
    bf16* wqkve = (bf16*)(ws + 209977344);    // 512 KB
    bf16* w2b   = (bf16*)(ws + 210501632);    // 256 KB
    bf16* posT  = (bf16*)(ws + 210763776);    //  64 KB [128][256]
    float* biasq= (float*)(ws + 210829312);   //   4 KB
    float* bn1s = (float*)(ws + 210833408);
    float* bn1h = (float*)(ws + 210834432);
    float* bn2s = (float*)(ws + 210835456);
    float* bn2h = (float*)(ws + 210837504);
    float* lsum = (float*)(ws + 210839552);   // 128 KB [2][4][4096] fp32

    prep_misc_kernel<<<2183, 256, 0, stream>>>(
        cv1_w, q_w, q_b, k_w, k_b, v_w, v_b, e_w, e_b, cv2_w,
        bn1_g, bn1_b, bn1_m, bn1_v, bn2_g, bn2_b, bn2_m, bn2_v,
        rel_h, rel_w,
        w1b, wqkve, w2b, posT, biasq, bn1s, bn1h, bn2s, bn2h);
    zero_lsum_kernel<<<128, 256, 0, stream>>>(lsum);
    transpose_x_kernel<<<dim3(64, 8, 8), 256, 0, stream>>>(x, xt);
    gemm1_kernel<<<dim3(2, 256), 256, 0, stream>>>(xt, w1b, bn1s, bn1h, x1t);
    gemm2_kernel<<<dim3(8, 256), 256, 0, stream>>>(x1t, wqkve, biasq, qk, v_nm, e_nm);
    gemm_rhw_kernel<<<dim3(32, 1, 8), 256, 0, stream>>>(posT, e_nm, rhwT);
    transpose_v_kernel<<<dim3(64, 4, 8), 256, 0, stream>>>(v_nm, v_cm);
    for (int g = 0; g < 2; ++g) {
        float* ls = lsum + (size_t)g * 4 * 4096;
        gemm3b_kernel<<<dim3(32, 32, 4), 256, 0, stream>>>(qk, rhwT, P, ls, g * 4);
        gemm4b_kernel<<<dim3(2, 32, 4), 256, 0, stream>>>(P, v_cm, ls, out_t, g * 4);
    }
    gemm5_kernel<<<dim3(32, 4, 8), 256, 0, stream>>>(w2b, out_t, bn2s, bn2h, x, out);
}